// Round 1
// baseline (1730.006 us; speedup 1.0000x reference)
//
#include <hip/hip_runtime.h>
#include <hip/hip_bf16.h>

#define VOCAB 10000
#define D 200
#define NLAYERS 3
#define NB 16
#define NS 512
#define M 8192        // NB*NS
#define KA 224        // padded K for A (h3 bf16), 7 * 32
#define KB 232        // padded K for fc_w bf16; 29 16B-chunks (odd -> no LDS bank conflicts)
#define NPADA 10120   // 79*128 = 10112, +8 rows slack for unguarded staging
#define NTILES_N 79

typedef __bf16 bf16x8 __attribute__((ext_vector_type(8)));
typedef float  f32x4  __attribute__((ext_vector_type(4)));
typedef unsigned int u32x4 __attribute__((ext_vector_type(4)));

// ---------------- embedding gather: h0[bs][d] = emb[x[bs]][d] ----------------
__global__ void k_embed(const int* __restrict__ x, const float* __restrict__ emb,
                        float* __restrict__ h0) {
    int i = blockIdx.x * blockDim.x + threadIdx.x;
    if (i < M * D) {
        int bs = i / D;
        int d  = i - bs * D;
        h0[i] = emb[(size_t)x[bs] * D + d];
    }
}

// ---------------- transpose w_ih: wt[l][k][n] = w_ih[l][n][k] ----------------
__global__ void k_wtrans(const float* __restrict__ w_ih, float* __restrict__ wt) {
    int i = blockIdx.x * blockDim.x + threadIdx.x;
    if (i < NLAYERS * D * D) {
        int l = i / (D * D);
        int r = i - l * D * D;
        int k = r / D;
        int n = r - k * D;
        wt[i] = w_ih[l * D * D + n * D + k];
    }
}

// ---------------- fc_w -> bf16, padded [NPADA][KB] ----------------
__global__ void k_fcwbf(const float* __restrict__ fc_w, __bf16* __restrict__ fwb) {
    int i = blockIdx.x * blockDim.x + threadIdx.x;
    if (i < NPADA * KB) {
        int n = i / KB;
        int k = i - n * KB;
        float v = (n < VOCAB && k < D) ? fc_w[(size_t)n * D + k] : 0.f;
        fwb[i] = (__bf16)v;
    }
}

// ---------------- h3 -> bf16, padded [M][KA] ----------------
__global__ void k_hbf(const float* __restrict__ h, __bf16* __restrict__ hbf) {
    int i = blockIdx.x * blockDim.x + threadIdx.x;
    if (i < M * KA) {
        int m = i >> 5;        // not power of 2... compute properly below
    }
    // (replaced by correct body)
}

// correct version (KA=224 not pow2): separate kernel body
__global__ void k_hbf2(const float* __restrict__ h, __bf16* __restrict__ hbf) {
    int i = blockIdx.x * blockDim.x + threadIdx.x;
    if (i < M * KA) {
        int m = i / KA;
        int k = i - m * KA;
        float v = (k < D) ? h[(size_t)m * D + k] : 0.f;
        hbf[i] = (__bf16)v;
    }
}

// ---------------- xw = h @ w_ih^T + b_ih + b_hh  (f32) ----------------
// grid 256 blocks (TILE_M=32), 256 threads; lane n computes col n for 32 rows.
__global__ void k_xw(const float* __restrict__ hin, const float* __restrict__ wt,
                     const float* __restrict__ b_ih, const float* __restrict__ b_hh,
                     float* __restrict__ xw) {
    int m0 = blockIdx.x * 32;
    int n  = threadIdx.x;
    if (n >= D) return;
    float bias = b_ih[n] + b_hh[n];
    for (int g = 0; g < 8; ++g) {
        const float* r0 = hin + (size_t)(m0 + g * 4) * D;
        float a0 = bias, a1 = bias, a2 = bias, a3 = bias;
        for (int k = 0; k < D; k += 4) {
            #pragma unroll
            for (int kk = 0; kk < 4; ++kk) {
                float w = wt[(k + kk) * D + n];      // coalesced, L2-resident
                float h0v = r0[k + kk];              // wave-uniform -> s_load
                float h1v = r0[D + k + kk];
                float h2v = r0[2 * D + k + kk];
                float h3v = r0[3 * D + k + kk];
                a0 += h0v * w; a1 += h1v * w; a2 += h2v * w; a3 += h3v * w;
            }
        }
        size_t o = (size_t)(m0 + g * 4) * D + n;
        xw[o] = a0; xw[o + D] = a1; xw[o + 2 * D] = a2; xw[o + 3 * D] = a3;
    }
}

// ---------------- recurrent scan, one workgroup per batch row ----------------
// io: xw in / h out (in place). whh: this layer's [D][D]. hidden: finals.
// 832 threads: t -> (h = t>>2, dg = t&3); lane holds w_hh[h][dstart..] in regs.
__device__ inline float fast_tanh(float x) {
    x = fminf(fmaxf(x, -15.f), 15.f);
    float e = __expf(2.f * x);
    return (e - 1.f) / (e + 1.f);
}

__global__ __launch_bounds__(832) void k_scan(const float* __restrict__ whh,
                                              float* __restrict__ io,
                                              float* __restrict__ hidden) {
    __shared__ float hp[2][208];   // double-buffered h_prev, padded to 208
    int t  = threadIdx.x;
    int b  = blockIdx.x;
    int h  = t >> 2;
    int dg = t & 3;
    bool active = (h < D);
    const int dstart = dg * 52;                 // chunks: 52,52,52,44 (16B aligned)
    float w[52];
    #pragma unroll
    for (int i = 0; i < 52; ++i) w[i] = 0.f;
    if (active) {
        #pragma unroll
        for (int i = 0; i < 44; ++i) w[i] = whh[h * D + dstart + i];
        if (dg < 3) {
            #pragma unroll
            for (int i = 44; i < 52; ++i) w[i] = whh[h * D + dstart + i];
        }
    }
    if (t < 208) { hp[0][t] = 0.f; hp[1][t] = 0.f; }
    __syncthreads();

    float* xrow = io + (size_t)b * NS * D;
    float xv_next = active ? xrow[h] : 0.f;     // prefetch s=0
    for (int s = 0; s < NS; ++s) {
        int cur = s & 1;
        float xv = xv_next;
        if (active && s + 1 < NS) xv_next = xrow[(size_t)(s + 1) * D + h];
        float acc = 0.f;
        if (active) {
            const float* hpc = &hp[cur][dstart];
            #pragma unroll
            for (int i = 0; i < 52; i += 4) {
                f32x4 h4 = *(const f32x4*)(hpc + i);   // ds_read_b128, pad reads *0
                acc += h4.x * w[i] + h4.y * w[i + 1] + h4.z * w[i + 2] + h4.w * w[i + 3];
            }
        }
        acc += __shfl_xor(acc, 1);
        acc += __shfl_xor(acc, 2);
        float hn = fast_tanh(xv + acc);
        if (active && dg == 0) {
            hp[1 - cur][h] = hn;
            xrow[(size_t)s * D + h] = hn;
            if (s == NS - 1) hidden[b * D + h] = hn;
        }
        __syncthreads();
    }
}

// ---------------- final FC: logits = h3_bf @ fcw_bf^T + fc_b (bf16 MFMA) -----
__global__ __launch_bounds__(256) void k_fc(const __bf16* __restrict__ A,
                                            const __bf16* __restrict__ Bw,
                                            const float* __restrict__ fc_b,
                                            float* __restrict__ Cout) {
    __shared__ __bf16 Bl[3840 * 8];            // 61440 B; tile uses 128*KB=29696
    int tid = threadIdx.x;
    int wg  = blockIdx.x;
    int mt  = wg / NTILES_N, nt = wg - mt * NTILES_N;
    int m0  = mt * 128, n0 = nt * 128;

    // stage B tile (linear 16B-chunk copy; 3840 chunks incl. slack)
    {
        const u32x4* src = (const u32x4*)(Bw + (size_t)n0 * KB);
        u32x4* dst = (u32x4*)Bl;
        u32x4 stg[15];
        #pragma unroll
        for (int it = 0; it < 15; ++it) stg[it] = src[tid + it * 256];
        #pragma unroll
        for (int it = 0; it < 15; ++it) dst[tid + it * 256] = stg[it];
    }
    __syncthreads();

    int lane = tid & 63, wv = tid >> 6;
    int wr = wv >> 1, wc = wv & 1;
    int lr = lane & 15, lq = lane >> 4;
    f32x4 acc[4][4] = {};
    #pragma unroll
    for (int ks = 0; ks < 7; ++ks) {
        bf16x8 af[4], bfr[4];
        #pragma unroll
        for (int i = 0; i < 4; ++i) {
            int arow = m0 + wr * 64 + i * 16 + lr;
            af[i] = *(const bf16x8*)(A + (size_t)arow * KA + (ks * 4 + lq) * 8);
            int brow = wc * 64 + i * 16 + lr;
            bfr[i] = *(const bf16x8*)(Bl + brow * KB + (ks * 4 + lq) * 8);
        }
        #pragma unroll
        for (int i = 0; i < 4; ++i) {
            #pragma unroll
            for (int j = 0; j < 4; ++j) {
                acc[i][j] = __builtin_amdgcn_mfma_f32_16x16x32_bf16(af[i], bfr[j],
                                                                   acc[i][j], 0, 0, 0);
            }
        }
    }
    #pragma unroll
    for (int j = 0; j < 4; ++j) {
        int col = n0 + wc * 64 + j * 16 + lr;
        if (col < VOCAB) {
            float bias = fc_b[col];
            #pragma unroll
            for (int i = 0; i < 4; ++i) {
                #pragma unroll
                for (int r = 0; r < 4; ++r) {
                    int row = m0 + wr * 64 + i * 16 + lq * 4 + r;
                    Cout[(size_t)row * VOCAB + col] = acc[i][j][r] + bias;
                }
            }
        }
    }
}

extern "C" void kernel_launch(void* const* d_in, const int* in_sizes, int n_in,
                              void* d_out, int out_size, void* d_ws, size_t ws_size,
                              hipStream_t stream) {
    const int*   x    = (const int*)  d_in[0];
    const float* emb  = (const float*)d_in[1];
    const float* w_ih = (const float*)d_in[2];
    const float* w_hh = (const float*)d_in[3];
    const float* b_ih = (const float*)d_in[4];
    const float* b_hh = (const float*)d_in[5];
    const float* fc_w = (const float*)d_in[6];
    const float* fc_b = (const float*)d_in[7];
    float* out    = (float*)d_out;
    float* hidden = out + (size_t)M * VOCAB;

    char* ws = (char*)d_ws;
    float*  buf0 = (float*)(ws);                                  // 6,553,600 B
    float*  buf1 = (float*)(ws + 6553600);                        // 6,553,600 B
    float*  wt   = (float*)(ws + 2 * 6553600);                    //   480,000 B
    __bf16* hbf  = (__bf16*)(ws + 2 * 6553600 + 480000);          // 3,670,016 B
    __bf16* fwb  = (__bf16*)(ws + 2 * 6553600 + 480000 + 3670016);// 4,695,680 B

    k_embed <<<(M * D + 255) / 256, 256, 0, stream>>>(x, emb, buf0);
    k_wtrans<<<(NLAYERS * D * D + 255) / 256, 256, 0, stream>>>(w_ih, wt);
    k_fcwbf <<<(NPADA * KB + 255) / 256, 256, 0, stream>>>(fc_w, fwb);

    float* cur = buf0;
    float* nxt = buf1;
    for (int l = 0; l < NLAYERS; ++l) {
        k_xw  <<<M / 32, 256, 0, stream>>>(cur, wt + l * D * D,
                                           b_ih + l * D, b_hh + l * D, nxt);
        k_scan<<<NB, 832, 0, stream>>>(w_hh + (size_t)l * D * D, nxt,
                                       hidden + l * NB * D);
        float* tswap = cur; cur = nxt; nxt = tswap;
    }
    k_hbf2<<<(M * KA + 255) / 256, 256, 0, stream>>>(cur, hbf);
    k_fc  <<<64 * NTILES_N, 256, 0, stream>>>(hbf, fwb, fc_b, out);
}

// Round 2
// 1380.934 us; speedup vs baseline: 1.2528x; 1.2528x over previous
//
#include <hip/hip_runtime.h>
#include <hip/hip_bf16.h>

#define VOCAB 10000
#define D 200
#define NLAYERS 3
#define NB 16
#define NS 512
#define M 8192        // NB*NS
#define KA 224        // padded K for A (h3 bf16), 7 * 32
#define KB 232        // padded K for fc_w bf16; 29 16B-chunks (odd -> no LDS bank conflicts)
#define NPADA 10120   // 79*128 = 10112, +8 rows slack for unguarded staging
#define NTILES_N 79

typedef __bf16 bf16x8 __attribute__((ext_vector_type(8)));
typedef float  f32x4  __attribute__((ext_vector_type(4)));
typedef unsigned int u32x4 __attribute__((ext_vector_type(4)));

// ---------------- embedding gather: h0[bs][d] = emb[x[bs]][d] ----------------
__global__ void k_embed(const int* __restrict__ x, const float* __restrict__ emb,
                        float* __restrict__ h0) {
    int i = blockIdx.x * blockDim.x + threadIdx.x;
    if (i < M * D) {
        int bs = i / D;
        int d  = i - bs * D;
        h0[i] = emb[(size_t)x[bs] * D + d];
    }
}

// ---------------- transpose w_ih: wt[l][k][n] = w_ih[l][n][k] ----------------
__global__ void k_wtrans(const float* __restrict__ w_ih, float* __restrict__ wt) {
    int i = blockIdx.x * blockDim.x + threadIdx.x;
    if (i < NLAYERS * D * D) {
        int l = i / (D * D);
        int r = i - l * D * D;
        int k = r / D;
        int n = r - k * D;
        wt[i] = w_ih[l * D * D + n * D + k];
    }
}

// ---------------- fc_w -> bf16, padded [NPADA][KB] ----------------
__global__ void k_fcwbf(const float* __restrict__ fc_w, __bf16* __restrict__ fwb) {
    int i = blockIdx.x * blockDim.x + threadIdx.x;
    if (i < NPADA * KB) {
        int n = i / KB;
        int k = i - n * KB;
        float v = (n < VOCAB && k < D) ? fc_w[(size_t)n * D + k] : 0.f;
        fwb[i] = (__bf16)v;
    }
}

// ---------------- h3 -> bf16, padded [M][KA] ----------------
__global__ void k_hbf2(const float* __restrict__ h, __bf16* __restrict__ hbf) {
    int i = blockIdx.x * blockDim.x + threadIdx.x;
    if (i < M * KA) {
        int m = i / KA;
        int k = i - m * KA;
        float v = (k < D) ? h[(size_t)m * D + k] : 0.f;
        hbf[i] = (__bf16)v;
    }
}

// ---------------- xw = h @ w_ih^T + b_ih + b_hh  (f32) ----------------
// grid 256 blocks (TILE_M=32), 256 threads; lane n computes col n for 32 rows.
__global__ void k_xw(const float* __restrict__ hin, const float* __restrict__ wt,
                     const float* __restrict__ b_ih, const float* __restrict__ b_hh,
                     float* __restrict__ xw) {
    int m0 = blockIdx.x * 32;
    int n  = threadIdx.x;
    if (n >= D) return;
    float bias = b_ih[n] + b_hh[n];
    for (int g = 0; g < 8; ++g) {
        const float* r0 = hin + (size_t)(m0 + g * 4) * D;
        float a0 = bias, a1 = bias, a2 = bias, a3 = bias;
        for (int k = 0; k < D; k += 4) {
            #pragma unroll
            for (int kk = 0; kk < 4; ++kk) {
                float w = wt[(k + kk) * D + n];      // coalesced, L2-resident
                float h0v = r0[k + kk];              // wave-uniform -> s_load
                float h1v = r0[D + k + kk];
                float h2v = r0[2 * D + k + kk];
                float h3v = r0[3 * D + k + kk];
                a0 += h0v * w; a1 += h1v * w; a2 += h2v * w; a3 += h3v * w;
            }
        }
        size_t o = (size_t)(m0 + g * 4) * D + n;
        xw[o] = a0; xw[o + D] = a1; xw[o + 2 * D] = a2; xw[o + 3 * D] = a3;
    }
}

// ---------------- recurrent scan, one workgroup per batch row ----------------
// io: xw in / h out (in place). whh: this layer's [D][D]. hidden: finals.
// 832 threads: t -> (h = t>>2, dg = t&3); lane holds 52 w_hh weights in 13
// f32x4 registers. __launch_bounds__(832,4): 13-wave block needs 4 waves on
// one SIMD -> VGPR cap 128; default heuristic gave 44 and SPILLED the weights
// (round-1 counters: FETCH 3.85 GB/dispatch of scratch reloads).
__device__ inline float fast_tanh(float x) {
    x = fminf(fmaxf(x, -15.f), 15.f);
    float e = __expf(2.f * x);
    return (e - 1.f) / (e + 1.f);
}

__global__ __launch_bounds__(832, 4) void k_scan(const float* __restrict__ whh,
                                                 float* __restrict__ io,
                                                 float* __restrict__ hidden) {
    __shared__ float hp[2][208];   // double-buffered h_prev; [200..207] stay 0
    int t  = threadIdx.x;
    int b  = blockIdx.x;
    int h  = t >> 2;
    int dg = t & 3;
    bool active = (h < D);
    const int dstart = dg * 52;    // dg==3 covers 156..207 (200..207 are zeros)

    f32x4 w4[13];
    #pragma unroll
    for (int i = 0; i < 13; ++i) w4[i] = f32x4{0.f, 0.f, 0.f, 0.f};
    if (active) {
        const float* wr = whh + h * D + dstart;
        #pragma unroll
        for (int i = 0; i < 11; ++i) w4[i] = *(const f32x4*)(wr + 4 * i);
        if (dg < 3) {              // dg==3 has only 44 real weights (156..199)
            w4[11] = *(const f32x4*)(wr + 44);
            w4[12] = *(const f32x4*)(wr + 48);
        }
    }
    if (t < 208) { hp[0][t] = 0.f; hp[1][t] = 0.f; }
    __syncthreads();

    float* xrow = io + (size_t)b * NS * D;
    float xv_next = active ? xrow[h] : 0.f;     // prefetch s=0
    for (int s = 0; s < NS; ++s) {
        int cur = s & 1;
        float xv = xv_next;
        if (active && s + 1 < NS) xv_next = xrow[(size_t)(s + 1) * D + h];
        float acc0 = 0.f, acc1 = 0.f, acc2 = 0.f, acc3 = 0.f;
        const float* hpc = &hp[cur][dstart];
        #pragma unroll
        for (int i = 0; i < 13; ++i) {          // 4 independent chains, len 13
            f32x4 h4 = *(const f32x4*)(hpc + 4 * i);   // ds_read_b128
            acc0 = fmaf(h4.x, w4[i].x, acc0);
            acc1 = fmaf(h4.y, w4[i].y, acc1);
            acc2 = fmaf(h4.z, w4[i].z, acc2);
            acc3 = fmaf(h4.w, w4[i].w, acc3);
        }
        float acc = (acc0 + acc1) + (acc2 + acc3);
        acc += __shfl_xor(acc, 1);
        acc += __shfl_xor(acc, 2);
        float hn = fast_tanh(xv + acc);
        if (active && dg == 0) {
            hp[1 - cur][h] = hn;
            xrow[(size_t)s * D + h] = hn;
            if (s == NS - 1) hidden[b * D + h] = hn;
        }
        __syncthreads();
    }
}

// ---------------- final FC: logits = h3_bf @ fcw_bf^T + fc_b (bf16 MFMA) -----
__global__ __launch_bounds__(256) void k_fc(const __bf16* __restrict__ A,
                                            const __bf16* __restrict__ Bw,
                                            const float* __restrict__ fc_b,
                                            float* __restrict__ Cout) {
    __shared__ __bf16 Bl[3840 * 8];            // 61440 B; tile uses 128*KB=29696
    int tid = threadIdx.x;
    int wg  = blockIdx.x;
    int mt  = wg / NTILES_N, nt = wg - mt * NTILES_N;
    int m0  = mt * 128, n0 = nt * 128;

    // stage B tile (linear 16B-chunk copy; 3840 chunks incl. slack)
    {
        const u32x4* src = (const u32x4*)(Bw + (size_t)n0 * KB);
        u32x4* dst = (u32x4*)Bl;
        u32x4 stg[15];
        #pragma unroll
        for (int it = 0; it < 15; ++it) stg[it] = src[tid + it * 256];
        #pragma unroll
        for (int it = 0; it < 15; ++it) dst[tid + it * 256] = stg[it];
    }
    __syncthreads();

    int lane = tid & 63, wv = tid >> 6;
    int wr = wv >> 1, wc = wv & 1;
    int lr = lane & 15, lq = lane >> 4;
    f32x4 acc[4][4] = {};
    #pragma unroll
    for (int ks = 0; ks < 7; ++ks) {
        bf16x8 af[4], bfr[4];
        #pragma unroll
        for (int i = 0; i < 4; ++i) {
            int arow = m0 + wr * 64 + i * 16 + lr;
            af[i] = *(const bf16x8*)(A + (size_t)arow * KA + (ks * 4 + lq) * 8);
            int brow = wc * 64 + i * 16 + lr;
            bfr[i] = *(const bf16x8*)(Bl + brow * KB + (ks * 4 + lq) * 8);
        }
        #pragma unroll
        for (int i = 0; i < 4; ++i) {
            #pragma unroll
            for (int j = 0; j < 4; ++j) {
                acc[i][j] = __builtin_amdgcn_mfma_f32_16x16x32_bf16(af[i], bfr[j],
                                                                   acc[i][j], 0, 0, 0);
            }
        }
    }
    #pragma unroll
    for (int j = 0; j < 4; ++j) {
        int col = n0 + wc * 64 + j * 16 + lr;
        if (col < VOCAB) {
            float bias = fc_b[col];
            #pragma unroll
            for (int i = 0; i < 4; ++i) {
                #pragma unroll
                for (int r = 0; r < 4; ++r) {
                    int row = m0 + wr * 64 + i * 16 + lq * 4 + r;
                    Cout[(size_t)row * VOCAB + col] = acc[i][j][r] + bias;
                }
            }
        }
    }
}

extern "C" void kernel_launch(void* const* d_in, const int* in_sizes, int n_in,
                              void* d_out, int out_size, void* d_ws, size_t ws_size,
                              hipStream_t stream) {
    const int*   x    = (const int*)  d_in[0];
    const float* emb  = (const float*)d_in[1];
    const float* w_ih = (const float*)d_in[2];
    const float* w_hh = (const float*)d_in[3];
    const float* b_ih = (const float*)d_in[4];
    const float* b_hh = (const float*)d_in[5];
    const float* fc_w = (const float*)d_in[6];
    const float* fc_b = (const float*)d_in[7];
    float* out    = (float*)d_out;
    float* hidden = out + (size_t)M * VOCAB;

    char* ws = (char*)d_ws;
    float*  buf0 = (float*)(ws);                                  // 6,553,600 B
    float*  buf1 = (float*)(ws + 6553600);                        // 6,553,600 B
    float*  wt   = (float*)(ws + 2 * 6553600);                    //   480,000 B
    __bf16* hbf  = (__bf16*)(ws + 2 * 6553600 + 480000);          // 3,670,016 B
    __bf16* fwb  = (__bf16*)(ws + 2 * 6553600 + 480000 + 3670016);// 4,695,680 B

    k_embed <<<(M * D + 255) / 256, 256, 0, stream>>>(x, emb, buf0);
    k_wtrans<<<(NLAYERS * D * D + 255) / 256, 256, 0, stream>>>(w_ih, wt);
    k_fcwbf <<<(NPADA * KB + 255) / 256, 256, 0, stream>>>(fc_w, fwb);

    float* cur = buf0;
    float* nxt = buf1;
    for (int l = 0; l < NLAYERS; ++l) {
        k_xw  <<<M / 32, 256, 0, stream>>>(cur, wt + l * D * D,
                                           b_ih + l * D, b_hh + l * D, nxt);
        k_scan<<<NB, 832, 0, stream>>>(w_hh + (size_t)l * D * D, nxt,
                                       hidden + l * NB * D);
        float* tswap = cur; cur = nxt; nxt = tswap;
    }
    k_hbf2<<<(M * KA + 255) / 256, 256, 0, stream>>>(cur, hbf);
    k_fc  <<<64 * NTILES_N, 256, 0, stream>>>(hbf, fwb, fc_b, out);
}

// Round 4
// 1322.186 us; speedup vs baseline: 1.3084x; 1.0444x over previous
//
#include <hip/hip_runtime.h>
#include <hip/hip_bf16.h>

#define VOCAB 10000
#define D 200
#define NLAYERS 3
#define NB 16
#define NS 512
#define M 8192        // NB*NS
#define KA 224        // padded K for A (h3 bf16), 7 * 32
#define KB 232        // padded K for fc_w bf16; 29 16B-chunks (odd -> no LDS bank conflicts)
#define NPADA 10120   // 79*128 = 10112, +8 rows slack for unguarded staging
#define NTILES_N 79

typedef __bf16 bf16x8 __attribute__((ext_vector_type(8)));
typedef float  f32x4  __attribute__((ext_vector_type(4)));
typedef unsigned int u32x4 __attribute__((ext_vector_type(4)));

// ---------------- embedding gather: h0[bs][d] = emb[x[bs]][d] ----------------
__global__ void k_embed(const int* __restrict__ x, const float* __restrict__ emb,
                        float* __restrict__ h0) {
    int i = blockIdx.x * blockDim.x + threadIdx.x;
    if (i < M * D) {
        int bs = i / D;
        int d  = i - bs * D;
        h0[i] = emb[(size_t)x[bs] * D + d];
    }
}

// ---------------- transpose w_ih: wt[l][k][n] = w_ih[l][n][k] ----------------
__global__ void k_wtrans(const float* __restrict__ w_ih, float* __restrict__ wt) {
    int i = blockIdx.x * blockDim.x + threadIdx.x;
    if (i < NLAYERS * D * D) {
        int l = i / (D * D);
        int r = i - l * D * D;
        int k = r / D;
        int n = r - k * D;
        wt[i] = w_ih[l * D * D + n * D + k];
    }
}

// ---------------- fc_w -> bf16, padded [NPADA][KB] ----------------
__global__ void k_fcwbf(const float* __restrict__ fc_w, __bf16* __restrict__ fwb) {
    int i = blockIdx.x * blockDim.x + threadIdx.x;
    if (i < NPADA * KB) {
        int n = i / KB;
        int k = i - n * KB;
        float v = (n < VOCAB && k < D) ? fc_w[(size_t)n * D + k] : 0.f;
        fwb[i] = (__bf16)v;
    }
}

// ---------------- h3 -> bf16, padded [M][KA] ----------------
__global__ void k_hbf2(const float* __restrict__ h, __bf16* __restrict__ hbf) {
    int i = blockIdx.x * blockDim.x + threadIdx.x;
    if (i < M * KA) {
        int m = i / KA;
        int k = i - m * KA;
        float v = (k < D) ? h[(size_t)m * D + k] : 0.f;
        hbf[i] = (__bf16)v;
    }
}

// ---------------- xw = h @ w_ih^T + b_ih + b_hh  (f32) ----------------
__global__ void k_xw(const float* __restrict__ hin, const float* __restrict__ wt,
                     const float* __restrict__ b_ih, const float* __restrict__ b_hh,
                     float* __restrict__ xw) {
    int m0 = blockIdx.x * 32;
    int n  = threadIdx.x;
    if (n >= D) return;
    float bias = b_ih[n] + b_hh[n];
    for (int g = 0; g < 8; ++g) {
        const float* r0 = hin + (size_t)(m0 + g * 4) * D;
        float a0 = bias, a1 = bias, a2 = bias, a3 = bias;
        for (int k = 0; k < D; k += 4) {
            #pragma unroll
            for (int kk = 0; kk < 4; ++kk) {
                float w = wt[(k + kk) * D + n];      // coalesced, L2-resident
                float h0v = r0[k + kk];              // wave-uniform
                float h1v = r0[D + k + kk];
                float h2v = r0[2 * D + k + kk];
                float h3v = r0[3 * D + k + kk];
                a0 += h0v * w; a1 += h1v * w; a2 += h2v * w; a3 += h3v * w;
            }
        }
        size_t o = (size_t)(m0 + g * 4) * D + n;
        xw[o] = a0; xw[o + D] = a1; xw[o + 2 * D] = a2; xw[o + 3 * D] = a3;
    }
}

// ---------------- recurrent scan, one workgroup per batch row ----------------
// 256 threads (4 waves, 1 per SIMD). Quad q owns output rows 4q..4q+3; lane dg
// holds k-slice [52*dg, 52*dg+52) of those 4 weight rows in registers (208
// VGPR; launch_bounds(256,1) -> no cap pressure). Per step: 13 broadcast
// ds_read_b128 of h_prev (all quads with equal dg read identical addresses),
// 52 vector FMAs, 4 verified __shfl_xor butterflies + select so lane t ends
// with output t. One barrier per step; hp double-buffered via 2-step unroll.
__device__ inline float fast_tanh(float x) {
    x = fminf(fmaxf(x, -15.f), 15.f);
    float e = __expf(2.f * x);
    return (e - 1.f) / (e + 1.f);
}

#define STEP(HR, HW, SIDX)                                                  \
    {                                                                       \
        float xv = xv_next;                                                 \
        int snext = (SIDX) + 1 < NS ? (SIDX) + 1 : NS - 1;                  \
        xv_next = xrow[(size_t)snext * D + tl];                             \
        f32x4 ac0{0.f,0.f,0.f,0.f}, ac1{0.f,0.f,0.f,0.f};                   \
        f32x4 ac2{0.f,0.f,0.f,0.f}, ac3{0.f,0.f,0.f,0.f};                   \
        _Pragma("unroll")                                                   \
        for (int i = 0; i < 13; ++i) {                                      \
            f32x4 h4 = *(const f32x4*)((HR) + 4 * i);                       \
            ac0 += h4 * w4[0][i];                                           \
            ac1 += h4 * w4[1][i];                                           \
            ac2 += h4 * w4[2][i];                                           \
            ac3 += h4 * w4[3][i];                                           \
        }                                                                   \
        float s0 = (ac0.x + ac0.y) + (ac0.z + ac0.w);                       \
        float s1 = (ac1.x + ac1.y) + (ac1.z + ac1.w);                       \
        float s2r = (ac2.x + ac2.y) + (ac2.z + ac2.w);                      \
        float s3 = (ac3.x + ac3.y) + (ac3.z + ac3.w);                       \
        s0 += __shfl_xor(s0, 1);  s0 += __shfl_xor(s0, 2);                  \
        s1 += __shfl_xor(s1, 1);  s1 += __shfl_xor(s1, 2);                  \
        s2r += __shfl_xor(s2r, 1); s2r += __shfl_xor(s2r, 2);               \
        s3 += __shfl_xor(s3, 1);  s3 += __shfl_xor(s3, 2);                  \
        float accv = dg == 0 ? s0 : dg == 1 ? s1 : dg == 2 ? s2r : s3;      \
        float hn = fast_tanh(xv + accv);                                    \
        hlast = hn;                                                         \
        if (act) {                                                          \
            (HW)[t] = hn;                                                   \
            xrow[(size_t)(SIDX) * D + t] = hn;                              \
        }                                                                   \
        __syncthreads();                                                    \
    }

__global__ __launch_bounds__(256, 1) void k_scan(const float* __restrict__ whh,
                                                 float* __restrict__ io,
                                                 float* __restrict__ hidden) {
    __shared__ float hp0[208], hp1[208];
    int t  = threadIdx.x;
    int b  = blockIdx.x;
    int q  = t >> 2;
    int dg = t & 3;
    const bool act = (t < D);
    const int tl = act ? t : 0;     // lane-clamped index: no OOB reads ever
    const int dstart = dg * 52;     // dg==3 covers 156..207 (200..207 stay zero)

    f32x4 w4[4][13];
    #pragma unroll
    for (int j = 0; j < 4; ++j)
        #pragma unroll
        for (int i = 0; i < 13; ++i) w4[j][i] = f32x4{0.f, 0.f, 0.f, 0.f};
    if (act) {
        #pragma unroll
        for (int j = 0; j < 4; ++j) {
            const float* wr = whh + (size_t)(4 * q + j) * D + dstart;
            #pragma unroll
            for (int i = 0; i < 11; ++i) w4[j][i] = *(const f32x4*)(wr + 4 * i);
            if (dg < 3) {           // dg==3 has only 44 real weights (156..199)
                w4[j][11] = *(const f32x4*)(wr + 44);
                w4[j][12] = *(const f32x4*)(wr + 48);
            }
        }
    }
    if (t < 208) { hp0[t] = 0.f; hp1[t] = 0.f; }
    __syncthreads();

    float* xrow = io + (size_t)b * NS * D;
    const float* hr0 = hp0 + dstart;
    const float* hr1 = hp1 + dstart;
    float xv_next = xrow[tl];       // prefetch s=0
    float hlast = 0.f;

    #pragma unroll 1
    for (int s2 = 0; s2 < NS / 2; ++s2) {
        STEP(hr0, hp1, 2 * s2)
        STEP(hr1, hp0, 2 * s2 + 1)
    }
    if (act) hidden[b * D + t] = hlast;
}

// ---------------- final FC: logits = h3_bf @ fcw_bf^T + fc_b (bf16 MFMA) -----
__global__ __launch_bounds__(256) void k_fc(const __bf16* __restrict__ A,
                                            const __bf16* __restrict__ Bw,
                                            const float* __restrict__ fc_b,
                                            float* __restrict__ Cout) {
    __shared__ __bf16 Bl[3840 * 8];            // 61440 B; tile uses 128*KB=29696
    int tid = threadIdx.x;
    int wg  = blockIdx.x;
    int mt  = wg / NTILES_N, nt = wg - mt * NTILES_N;
    int m0  = mt * 128, n0 = nt * 128;

    // stage B tile (linear 16B-chunk copy; 3840 chunks incl. slack)
    {
        const u32x4* src = (const u32x4*)(Bw + (size_t)n0 * KB);
        u32x4* dst = (u32x4*)Bl;
        u32x4 stg[15];
        #pragma unroll
        for (int it = 0; it < 15; ++it) stg[it] = src[tid + it * 256];
        #pragma unroll
        for (int it = 0; it < 15; ++it) dst[tid + it * 256] = stg[it];
    }
    __syncthreads();

    int lane = tid & 63, wv = tid >> 6;
    int wr = wv >> 1, wc = wv & 1;
    int lr = lane & 15, lq = lane >> 4;
    f32x4 acc[4][4] = {};
    #pragma unroll
    for (int ks = 0; ks < 7; ++ks) {
        bf16x8 af[4], bfr[4];
        #pragma unroll
        for (int i = 0; i < 4; ++i) {
            int arow = m0 + wr * 64 + i * 16 + lr;
            af[i] = *(const bf16x8*)(A + (size_t)arow * KA + (ks * 4 + lq) * 8);
            int brow = wc * 64 + i * 16 + lr;
            bfr[i] = *(const bf16x8*)(Bl + brow * KB + (ks * 4 + lq) * 8);
        }
        #pragma unroll
        for (int i = 0; i < 4; ++i) {
            #pragma unroll
            for (int j = 0; j < 4; ++j) {
                acc[i][j] = __builtin_amdgcn_mfma_f32_16x16x32_bf16(af[i], bfr[j],
                                                                   acc[i][j], 0, 0, 0);
            }
        }
    }
    #pragma unroll
    for (int j = 0; j < 4; ++j) {
        int col = n0 + wc * 64 + j * 16 + lr;
        if (col < VOCAB) {
            float bias = fc_b[col];
            #pragma unroll
            for (int i = 0; i < 4; ++i) {
                #pragma unroll
                for (int r = 0; r < 4; ++r) {
                    int row = m0 + wr * 64 + i * 16 + lq * 4 + r;
                    Cout[(size_t)row * VOCAB + col] = acc[i][j][r] + bias;
                }
            }
        }
    }
}

extern "C" void kernel_launch(void* const* d_in, const int* in_sizes, int n_in,
                              void* d_out, int out_size, void* d_ws, size_t ws_size,
                              hipStream_t stream) {
    const int*   x    = (const int*)  d_in[0];
    const float* emb  = (const float*)d_in[1];
    const float* w_ih = (const float*)d_in[2];
    const float* w_hh = (const float*)d_in[3];
    const float* b_ih = (const float*)d_in[4];
    const float* b_hh = (const float*)d_in[5];
    const float* fc_w = (const float*)d_in[6];
    const float* fc_b = (const float*)d_in[7];
    float* out    = (float*)d_out;
    float* hidden = out + (size_t)M * VOCAB;

    char* ws = (char*)d_ws;
    float*  buf0 = (float*)(ws);                                  // 6,553,600 B
    float*  buf1 = (float*)(ws + 6553600);                        // 6,553,600 B
    float*  wt   = (float*)(ws + 2 * 6553600);                    //   480,000 B
    __bf16* hbf  = (__bf16*)(ws + 2 * 6553600 + 480000);          // 3,670,016 B
    __bf16* fwb  = (__bf16*)(ws + 2 * 6553600 + 480000 + 3670016);// 4,695,680 B

    k_embed <<<(M * D + 255) / 256, 256, 0, stream>>>(x, emb, buf0);
    k_wtrans<<<(NLAYERS * D * D + 255) / 256, 256, 0, stream>>>(w_ih, wt);
    k_fcwbf <<<(NPADA * KB + 255) / 256, 256, 0, stream>>>(fc_w, fwb);

    float* cur = buf0;
    float* nxt = buf1;
    for (int l = 0; l < NLAYERS; ++l) {
        k_xw  <<<M / 32, 256, 0, stream>>>(cur, wt + l * D * D,
                                           b_ih + l * D, b_hh + l * D, nxt);
        k_scan<<<NB, 256, 0, stream>>>(w_hh + (size_t)l * D * D, nxt,
                                       hidden + l * NB * D);
        float* tswap = cur; cur = nxt; nxt = tswap;
    }
    k_hbf2<<<(M * KA + 255) / 256, 256, 0, stream>>>(cur, hbf);
    k_fc  <<<64 * NTILES_N, 256, 0, stream>>>(hbf, fwb, fc_b, out);
}

// Round 5
// 1182.070 us; speedup vs baseline: 1.4635x; 1.1185x over previous
//
#include <hip/hip_runtime.h>
#include <hip/hip_bf16.h>

#define VOCAB 10000
#define D 200
#define NLAYERS 3
#define NB 16
#define NS 512
#define M 8192        // NB*NS
#define KA 224        // padded K for A (h3 bf16), 7 * 32
#define KB 232        // padded K for fc_w bf16; 29 16B-chunks (odd -> no LDS bank conflicts)
#define NPADA 10120   // 79*128 = 10112, +8 rows slack for unguarded staging
#define NTILES_N 79

typedef __bf16 bf16x8 __attribute__((ext_vector_type(8)));
typedef float  f32x4  __attribute__((ext_vector_type(4)));
typedef unsigned int u32x4 __attribute__((ext_vector_type(4)));

// ---------------- embedding gather: h0[bs][d] = emb[x[bs]][d] ----------------
__global__ void k_embed(const int* __restrict__ x, const float* __restrict__ emb,
                        float* __restrict__ h0) {
    int i = blockIdx.x * blockDim.x + threadIdx.x;
    if (i < M * D) {
        int bs = i / D;
        int d  = i - bs * D;
        h0[i] = emb[(size_t)x[bs] * D + d];
    }
}

// ---------------- transpose w_ih: wt[l][k][n] = w_ih[l][n][k] ----------------
__global__ void k_wtrans(const float* __restrict__ w_ih, float* __restrict__ wt) {
    int i = blockIdx.x * blockDim.x + threadIdx.x;
    if (i < NLAYERS * D * D) {
        int l = i / (D * D);
        int r = i - l * D * D;
        int k = r / D;
        int n = r - k * D;
        wt[i] = w_ih[l * D * D + n * D + k];
    }
}

// ---------------- fc_w -> bf16, padded [NPADA][KB] ----------------
__global__ void k_fcwbf(const float* __restrict__ fc_w, __bf16* __restrict__ fwb) {
    int i = blockIdx.x * blockDim.x + threadIdx.x;
    if (i < NPADA * KB) {
        int n = i / KB;
        int k = i - n * KB;
        float v = (n < VOCAB && k < D) ? fc_w[(size_t)n * D + k] : 0.f;
        fwb[i] = (__bf16)v;
    }
}

// ---------------- h3 -> bf16, padded [M][KA] ----------------
__global__ void k_hbf2(const float* __restrict__ h, __bf16* __restrict__ hbf) {
    int i = blockIdx.x * blockDim.x + threadIdx.x;
    if (i < M * KA) {
        int m = i / KA;
        int k = i - m * KA;
        float v = (k < D) ? h[(size_t)m * D + k] : 0.f;
        hbf[i] = (__bf16)v;
    }
}

// ---------------- xw = h @ w_ih^T + b_ih + b_hh  (f32) ----------------
__global__ void k_xw(const float* __restrict__ hin, const float* __restrict__ wt,
                     const float* __restrict__ b_ih, const float* __restrict__ b_hh,
                     float* __restrict__ xw) {
    int m0 = blockIdx.x * 32;
    int n  = threadIdx.x;
    if (n >= D) return;
    float bias = b_ih[n] + b_hh[n];
    for (int g = 0; g < 8; ++g) {
        const float* r0 = hin + (size_t)(m0 + g * 4) * D;
        float a0 = bias, a1 = bias, a2 = bias, a3 = bias;
        for (int k = 0; k < D; k += 4) {
            #pragma unroll
            for (int kk = 0; kk < 4; ++kk) {
                float w = wt[(k + kk) * D + n];      // coalesced, L2-resident
                float h0v = r0[k + kk];              // wave-uniform
                float h1v = r0[D + k + kk];
                float h2v = r0[2 * D + k + kk];
                float h3v = r0[3 * D + k + kk];
                a0 += h0v * w; a1 += h1v * w; a2 += h2v * w; a3 += h3v * w;
            }
        }
        size_t o = (size_t)(m0 + g * 4) * D + n;
        xw[o] = a0; xw[o + D] = a1; xw[o + 2 * D] = a2; xw[o + 3 * D] = a3;
    }
}

// ---------------- recurrent scan, one workgroup per batch row ----------------
// 512 threads (8 waves, 2 per SIMD). Quad q owns output rows 2q, 2q+1; lane dg
// holds k-slice [52*dg, 52*dg+52) of BOTH rows in 26 f32x4 = 104 VGPRs (+~40
// temps -> ~150, well under the 256 cap at 2 waves/EU; round-4's 208-VGPR
// array got silently demoted -> VGPR_Count=128 and ~2x VALU issue). Per step:
// 13 broadcast ds_read_b128 of h_prev, 52 vec-FMAs, 2x2 __shfl_xor butterfly;
// lane dg picks row 2q+(dg&1) which matches its prefetched x value; dg<2
// lanes write. One barrier per step; hp double-buffered via 2-step unroll.
__device__ inline float fast_tanh(float x) {
    x = fminf(fmaxf(x, -15.f), 15.f);
    float e = __expf(2.f * x);
    return (e - 1.f) / (e + 1.f);
}

#define STEP(HR, HW, SIDX)                                                  \
    {                                                                       \
        float xv = xv_next;                                                 \
        int snext = (SIDX) + 1 < NS ? (SIDX) + 1 : NS - 1;                  \
        xv_next = xrow[(size_t)snext * D + rrl];                            \
        f32x4 ac0{0.f,0.f,0.f,0.f}, ac1{0.f,0.f,0.f,0.f};                   \
        _Pragma("unroll")                                                   \
        for (int i = 0; i < 13; ++i) {                                      \
            f32x4 h4 = *(const f32x4*)((HR) + 4 * i);                       \
            ac0 += h4 * w4[0][i];                                           \
            ac1 += h4 * w4[1][i];                                           \
        }                                                                   \
        float s0 = (ac0.x + ac0.y) + (ac0.z + ac0.w);                       \
        float s1 = (ac1.x + ac1.y) + (ac1.z + ac1.w);                       \
        s0 += __shfl_xor(s0, 1);  s0 += __shfl_xor(s0, 2);                  \
        s1 += __shfl_xor(s1, 1);  s1 += __shfl_xor(s1, 2);                  \
        float hn = fast_tanh(xv + ((dg & 1) ? s1 : s0));                    \
        hlast = hn;                                                         \
        if (wlane) {                                                        \
            (HW)[rr] = hn;                                                  \
            xrow[(size_t)(SIDX) * D + rr] = hn;                             \
        }                                                                   \
        __syncthreads();                                                    \
    }

__global__ __launch_bounds__(512, 2) void k_scan(const float* __restrict__ whh,
                                                 float* __restrict__ io,
                                                 float* __restrict__ hidden) {
    __shared__ float hp0[208], hp1[208];
    int t  = threadIdx.x;
    int b  = blockIdx.x;
    int q  = t >> 2;
    int dg = t & 3;
    const bool act = (q < 100);          // quads 0..99 cover rows 0..199
    const int  rr  = 2 * q + (dg & 1);   // row this lane selects / writes
    const int  rrl = act ? rr : 0;       // clamped for loads: no OOB ever
    const bool wlane = act && (dg < 2);  // distinct writer lane per row
    const int  dstart = dg * 52;         // dg==3 covers 156..207 (200.. stay 0)

    f32x4 w4[2][13];
    #pragma unroll
    for (int j = 0; j < 2; ++j)
        #pragma unroll
        for (int i = 0; i < 13; ++i) w4[j][i] = f32x4{0.f, 0.f, 0.f, 0.f};
    if (act) {
        #pragma unroll
        for (int j = 0; j < 2; ++j) {
            const float* wr = whh + (size_t)(2 * q + j) * D + dstart;
            #pragma unroll
            for (int i = 0; i < 11; ++i) w4[j][i] = *(const f32x4*)(wr + 4 * i);
            if (dg < 3) {            // dg==3 has only 44 real weights (156..199)
                w4[j][11] = *(const f32x4*)(wr + 44);
                w4[j][12] = *(const f32x4*)(wr + 48);
            }
        }
    }
    if (t < 208) { hp0[t] = 0.f; hp1[t] = 0.f; }
    __syncthreads();

    float* xrow = io + (size_t)b * NS * D;
    const float* hr0 = hp0 + dstart;
    const float* hr1 = hp1 + dstart;
    float xv_next = xrow[rrl];           // prefetch s=0
    float hlast = 0.f;

    #pragma unroll 1
    for (int s2 = 0; s2 < NS / 2; ++s2) {
        STEP(hr0, hp1, 2 * s2)
        STEP(hr1, hp0, 2 * s2 + 1)
    }
    if (wlane) hidden[b * D + rr] = hlast;
}

// ---------------- final FC: logits = h3_bf @ fcw_bf^T + fc_b (bf16 MFMA) -----
__global__ __launch_bounds__(256) void k_fc(const __bf16* __restrict__ A,
                                            const __bf16* __restrict__ Bw,
                                            const float* __restrict__ fc_b,
                                            float* __restrict__ Cout) {
    __shared__ __bf16 Bl[3840 * 8];            // 61440 B; tile uses 128*KB=29696
    int tid = threadIdx.x;
    int wg  = blockIdx.x;
    int mt  = wg / NTILES_N, nt = wg - mt * NTILES_N;
    int m0  = mt * 128, n0 = nt * 128;

    // stage B tile (linear 16B-chunk copy; 3840 chunks incl. slack)
    {
        const u32x4* src = (const u32x4*)(Bw + (size_t)n0 * KB);
        u32x4* dst = (u32x4*)Bl;
        u32x4 stg[15];
        #pragma unroll
        for (int it = 0; it < 15; ++it) stg[it] = src[tid + it * 256];
        #pragma unroll
        for (int it = 0; it < 15; ++it) dst[tid + it * 256] = stg[it];
    }
    __syncthreads();

    int lane = tid & 63, wv = tid >> 6;
    int wr = wv >> 1, wc = wv & 1;
    int lr = lane & 15, lq = lane >> 4;
    f32x4 acc[4][4] = {};
    #pragma unroll
    for (int ks = 0; ks < 7; ++ks) {
        bf16x8 af[4], bfr[4];
        #pragma unroll
        for (int i = 0; i < 4; ++i) {
            int arow = m0 + wr * 64 + i * 16 + lr;
            af[i] = *(const bf16x8*)(A + (size_t)arow * KA + (ks * 4 + lq) * 8);
            int brow = wc * 64 + i * 16 + lr;
            bfr[i] = *(const bf16x8*)(Bl + brow * KB + (ks * 4 + lq) * 8);
        }
        #pragma unroll
        for (int i = 0; i < 4; ++i) {
            #pragma unroll
            for (int j = 0; j < 4; ++j) {
                acc[i][j] = __builtin_amdgcn_mfma_f32_16x16x32_bf16(af[i], bfr[j],
                                                                   acc[i][j], 0, 0, 0);
            }
        }
    }
    #pragma unroll
    for (int j = 0; j < 4; ++j) {
        int col = n0 + wc * 64 + j * 16 + lr;
        if (col < VOCAB) {
            float bias = fc_b[col];
            #pragma unroll
            for (int i = 0; i < 4; ++i) {
                #pragma unroll
                for (int r = 0; r < 4; ++r) {
                    int row = m0 + wr * 64 + i * 16 + lq * 4 + r;
                    Cout[(size_t)row * VOCAB + col] = acc[i][j][r] + bias;
                }
            }
        }
    }
}

extern "C" void kernel_launch(void* const* d_in, const int* in_sizes, int n_in,
                              void* d_out, int out_size, void* d_ws, size_t ws_size,
                              hipStream_t stream) {
    const int*   x    = (const int*)  d_in[0];
    const float* emb  = (const float*)d_in[1];
    const float* w_ih = (const float*)d_in[2];
    const float* w_hh = (const float*)d_in[3];
    const float* b_ih = (const float*)d_in[4];
    const float* b_hh = (const float*)d_in[5];
    const float* fc_w = (const float*)d_in[6];
    const float* fc_b = (const float*)d_in[7];
    float* out    = (float*)d_out;
    float* hidden = out + (size_t)M * VOCAB;

    char* ws = (char*)d_ws;
    float*  buf0 = (float*)(ws);                                  // 6,553,600 B
    float*  buf1 = (float*)(ws + 6553600);                        // 6,553,600 B
    float*  wt   = (float*)(ws + 2 * 6553600);                    //   480,000 B
    __bf16* hbf  = (__bf16*)(ws + 2 * 6553600 + 480000);          // 3,670,016 B
    __bf16* fwb  = (__bf16*)(ws + 2 * 6553600 + 480000 + 3670016);// 4,695,680 B

    k_embed <<<(M * D + 255) / 256, 256, 0, stream>>>(x, emb, buf0);
    k_wtrans<<<(NLAYERS * D * D + 255) / 256, 256, 0, stream>>>(w_ih, wt);
    k_fcwbf <<<(NPADA * KB + 255) / 256, 256, 0, stream>>>(fc_w, fwb);

    float* cur = buf0;
    float* nxt = buf1;
    for (int l = 0; l < NLAYERS; ++l) {
        k_xw  <<<M / 32, 256, 0, stream>>>(cur, wt + l * D * D,
                                           b_ih + l * D, b_hh + l * D, nxt);
        k_scan<<<NB, 512, 0, stream>>>(w_hh + (size_t)l * D * D, nxt,
                                       hidden + l * NB * D);
        float* tswap = cur; cur = nxt; nxt = tswap;
    }
    k_hbf2<<<(M * KA + 255) / 256, 256, 0, stream>>>(cur, hbf);
    k_fc  <<<64 * NTILES_N, 256, 0, stream>>>(hbf, fwb, fc_b, out);
}